// Round 5
// baseline (2933.182 us; speedup 1.0000x reference)
//
#include <hip/hip_runtime.h>
#include <hip/hip_bf16.h>
#include <cstdint>
#include <cstddef>

// Problem constants
#define BSZ  256
#define TDIM 128
#define DDIM 256
#define HIDN 256
#define G3   768   // 3*HID

using bf16x8 = __attribute__((ext_vector_type(8))) short;   // 8 bf16 in 4 VGPRs
using f32x4  = __attribute__((ext_vector_type(4))) float;   // MFMA accumulator

__device__ __forceinline__ unsigned short f2bf(float f) {
  union { float f; unsigned u; } x; x.f = f;
  unsigned r = x.u + 0x7FFFu + ((x.u >> 16) & 1u);   // RNE, inputs are sane
  return (unsigned short)(r >> 16);
}
__device__ __forceinline__ float bf2f_s(unsigned short u) {
  union { unsigned u; float f; } t; t.u = ((unsigned)u) << 16; return t.f;
}
__device__ __forceinline__ float sigm(float x) {
  return __builtin_amdgcn_rcpf(1.f + __expf(-x));
}
__device__ __forceinline__ float tanh_f(float x) {
  float e = __expf(2.f * x);
  return 1.f - 2.f * __builtin_amdgcn_rcpf(e + 1.f);
}
__device__ __forceinline__ float gelu_f(float x) {
  return 0.5f * x * (1.f + erff(x * 0.70710678118654752f));
}

// ---------------- fused fp32 -> bf16 convert (P + 8 weight tensors) ----------------
// spans are in float4 units: P 2097152 -> 8192 blocks; 768x256 -> 49152 -> 192; 256x256 -> 16384 -> 64
__global__ __launch_bounds__(256) void cvt_all(
    const float* __restrict__ P,  unsigned short* __restrict__ Pd,
    const float* __restrict__ a0, unsigned short* __restrict__ d0,
    const float* __restrict__ a1, unsigned short* __restrict__ d1,
    const float* __restrict__ a2, unsigned short* __restrict__ d2,
    const float* __restrict__ a3, unsigned short* __restrict__ d3,
    const float* __restrict__ a4, unsigned short* __restrict__ d4,
    const float* __restrict__ a5, unsigned short* __restrict__ d5,
    const float* __restrict__ a6, unsigned short* __restrict__ d6,
    const float* __restrict__ a7, unsigned short* __restrict__ d7)
{
  const int blk = blockIdx.x;
  const float4* s; ushort4* d; int i;
  if      (blk < 8192) { s = (const float4*)P;  d = (ushort4*)Pd; i = blk * 256; }
  else if (blk < 8384) { s = (const float4*)a0; d = (ushort4*)d0; i = (blk - 8192) * 256; }
  else if (blk < 8576) { s = (const float4*)a1; d = (ushort4*)d1; i = (blk - 8384) * 256; }
  else if (blk < 8768) { s = (const float4*)a2; d = (ushort4*)d2; i = (blk - 8576) * 256; }
  else if (blk < 8960) { s = (const float4*)a3; d = (ushort4*)d3; i = (blk - 8768) * 256; }
  else if (blk < 9024) { s = (const float4*)a4; d = (ushort4*)d4; i = (blk - 8960) * 256; }
  else if (blk < 9088) { s = (const float4*)a5; d = (ushort4*)d5; i = (blk - 9024) * 256; }
  else if (blk < 9152) { s = (const float4*)a6; d = (ushort4*)d6; i = (blk - 9088) * 256; }
  else                 { s = (const float4*)a7; d = (ushort4*)d7; i = (blk - 9152) * 256; }
  i += threadIdx.x;
  float4 v = s[i];
  ushort4 o;
  o.x = f2bf(v.x); o.y = f2bf(v.y); o.z = f2bf(v.z); o.w = f2bf(v.w);
  d[i] = o;
}

// ---------------- bf16 -> fp32 expand (for Hout); n8 = total/8 ----------------
__global__ __launch_bounds__(256) void bf2f(const unsigned short* __restrict__ s,
                                            float* __restrict__ d, int n8) {
  int i = blockIdx.x * 256 + threadIdx.x;
  if (i >= n8) return;
  ushort4 a = ((const ushort4*)s)[i * 2];
  ushort4 b = ((const ushort4*)s)[i * 2 + 1];
  float4 o0, o1;
  o0.x = bf2f_s(a.x); o0.y = bf2f_s(a.y); o0.z = bf2f_s(a.z); o0.w = bf2f_s(a.w);
  o1.x = bf2f_s(b.x); o1.y = bf2f_s(b.y); o1.z = bf2f_s(b.z); o1.w = bf2f_s(b.w);
  ((float4*)d)[i * 2] = o0;
  ((float4*)d)[i * 2 + 1] = o1;
}

// ---------------- async global->LDS staging ----------------
#if defined(__has_builtin)
#if __has_builtin(__builtin_amdgcn_global_load_lds)
#define HAVE_GLL 1
#endif
#endif
#ifndef HAVE_GLL
#define HAVE_GLL 0
#endif

__device__ __forceinline__ void stage16(const unsigned short* gp,
                                        unsigned short* lbase, int lane) {
#if HAVE_GLL
  __builtin_amdgcn_global_load_lds((const __attribute__((address_space(1))) void*)gp,
                                   (__attribute__((address_space(3))) void*)lbase, 16, 0, 0);
#else
  *(bf16x8*)(lbase + lane * 8) = *(const bf16x8*)gp;
#endif
}

// ---------------- bf16 MFMA GEMM: C[m,n] = sum_k A[m,k]*B[n,k] (+bias, +gelu) ----------------
// 128x128 tile, BK=32, 256 threads (4 waves, each 64x64), chunk-major LDS (conflict-free b128).
__global__ __launch_bounds__(256) void gemm_bf16(
    const unsigned short* __restrict__ A, int lda,
    const unsigned short* __restrict__ B, int ldb,
    const float* __restrict__ bias,
    float* __restrict__ Cf, unsigned short* __restrict__ Cbf,
    int K, int ldc, int do_gelu)
{
  __shared__ unsigned short As[4096], Bs[4096];   // 8KB each: [chunk c][row r] 16B slots
  const int tid = threadIdx.x;
  const int w = tid >> 6, lane = tid & 63;
  const int m16 = lane & 15, quad = lane >> 4;
  const int m0 = blockIdx.y * 128, n0 = blockIdx.x * 128;
  const int wm = w >> 1, wn = w & 1;

  const f32x4 z4 = {0.f, 0.f, 0.f, 0.f};
  f32x4 acc[4][4];
#pragma unroll
  for (int i = 0; i < 4; ++i)
#pragma unroll
    for (int j = 0; j < 4; ++j) acc[i][j] = z4;

  const int nk = K >> 5;
  for (int kk = 0; kk < nk; ++kk) {
#pragma unroll
    for (int i = 0; i < 2; ++i) {
      const int r = i * 64 + lane;                 // row within tile
      stage16(A + (size_t)(m0 + r) * lda + kk * 32 + w * 8, &As[w * 1024 + i * 512], lane);
      stage16(B + (size_t)(n0 + r) * ldb + kk * 32 + w * 8, &Bs[w * 1024 + i * 512], lane);
    }
    __syncthreads();
    bf16x8 af[4], bfr[4];
#pragma unroll
    for (int i = 0; i < 4; ++i) {
      af[i]  = *(const bf16x8*)&As[quad * 1024 + (wm * 64 + i * 16 + m16) * 8];
      bfr[i] = *(const bf16x8*)&Bs[quad * 1024 + (wn * 64 + i * 16 + m16) * 8];
    }
#pragma unroll
    for (int i = 0; i < 4; ++i)
#pragma unroll
      for (int j = 0; j < 4; ++j)
        acc[i][j] = __builtin_amdgcn_mfma_f32_16x16x32_bf16(af[i], bfr[j], acc[i][j], 0, 0, 0);
    __syncthreads();
  }

#pragma unroll
  for (int i = 0; i < 4; ++i) {
    const int row0 = m0 + wm * 64 + i * 16 + quad * 4;
#pragma unroll
    for (int j = 0; j < 4; ++j) {
      const int col = n0 + wn * 64 + j * 16 + m16;
#pragma unroll
      for (int rg = 0; rg < 4; ++rg) {
        float v = acc[i][j][rg];
        if (bias) v += bias[col];
        if (do_gelu) v = gelu_f(v);
        const size_t off = (size_t)(row0 + rg) * ldc + col;
        if (Cf)  Cf[off] = v;
        if (Cbf) Cbf[off] = f2bf(v);
      }
    }
  }
}

// ---------------- GRU recurrence: weight-stationary col-split ----------------
// 16 blocks x 512 thr. Block owns 16 hidden cols (r,z,n rows -> 24 KB LDS, loaded once).
// Per step: read full h_t (256x256 bf16) via agent-scope 8B atomic loads from the
// IF-coherent exchange buffer Hx (double-buffered), MFMA (2 m-tiles/wave x 3 gates x 8 kk),
// write own 16 cols back with agent-scope atomic stores, then flag done[t+1].
// Safety: done[t]==16 gate means no block enters step t until ALL finished step t-1,
// so readers of h_t and writers of h_{t+1} never touch the same parity buffer.
// __syncthreads() drains vmcnt(0) per wave before the flag add (data-before-flag).
__global__ __launch_bounds__(512) void gru_rec(
    const float* __restrict__ gi,            // (BS*T, 768) natural, bih already added
    const unsigned short* __restrict__ Whh,  // (768, 256) bf16
    const float* __restrict__ bhh,           // (768,)
    unsigned short* __restrict__ Hbf,        // (BS,T,HID) bf16 out
    unsigned short* Hx,                      // (2,256,256) bf16 exchange
    unsigned int* flag)                      // [129], zero-initialized
{
  __shared__ unsigned short wlds[12288];     // 24 KB: slot s=g*512+c*16+cl holds 8 k-els
  const int tid = threadIdx.x;
  const int w = tid >> 6, lane = tid & 63;
  const int m16 = lane & 15, quad = lane >> 4;
  const int col = blockIdx.x * 16 + m16;

  for (int s = tid; s < 1536; s += 512) {
    const int g = s >> 9, c = (s >> 4) & 31, cl = s & 15;
    *(bf16x8*)&wlds[s * 8] =
        *(const bf16x8*)&Whh[(size_t)(g * 256 + blockIdx.x * 16 + cl) * 256 + c * 8];
  }
  float bb[3];
#pragma unroll
  for (int g = 0; g < 3; ++g) bb[g] = bhh[g * 256 + col];

  // t-invariant per-lane bases
  int gbase[2][4];                           // gi float index (fits in int: <26M)
#pragma unroll
  for (int mt = 0; mt < 2; ++mt)
#pragma unroll
    for (int rg = 0; rg < 4; ++rg) {
      const int row = w * 32 + mt * 16 + quad * 4 + rg;
      gbase[mt][rg] = row * 128 * 768 + col;
    }
  unsigned long long* hx64 = (unsigned long long*)Hx;
  int hread[2];                              // u64 index base for A-frag rows
#pragma unroll
  for (int mt = 0; mt < 2; ++mt)
    hread[mt] = (((w * 32 + mt * 16 + m16) * 256 + quad * 8) >> 2);

  float hreg[2][4] = {};
  const f32x4 z4 = {0.f, 0.f, 0.f, 0.f};
  __syncthreads();

  for (int t = 0; t < TDIM; ++t) {
    float gv[2][3][4];
#pragma unroll
    for (int mt = 0; mt < 2; ++mt)
#pragma unroll
      for (int g = 0; g < 3; ++g)
#pragma unroll
        for (int rg = 0; rg < 4; ++rg)
          gv[mt][g][rg] = gi[gbase[mt][rg] + t * 768 + g * 256];

    f32x4 acc[2][3];
#pragma unroll
    for (int mt = 0; mt < 2; ++mt)
#pragma unroll
      for (int g = 0; g < 3; ++g) acc[mt][g] = z4;

    if (t) {
      unsigned int* fl = &flag[t];
      while (__hip_atomic_load(fl, __ATOMIC_RELAXED, __HIP_MEMORY_SCOPE_AGENT) < 16u)
        __builtin_amdgcn_s_sleep(1);
      (void)__hip_atomic_load(fl, __ATOMIC_ACQUIRE, __HIP_MEMORY_SCOPE_AGENT);
      const int pb = (t & 1) * 16384;        // u64 offset of read buffer
#pragma unroll
      for (int kk = 0; kk < 8; ++kk) {
        union { unsigned long long q[2]; bf16x8 v; } ua, ub;
        ua.q[0] = __hip_atomic_load(&hx64[pb + hread[0] + kk * 8],     __ATOMIC_RELAXED, __HIP_MEMORY_SCOPE_AGENT);
        ua.q[1] = __hip_atomic_load(&hx64[pb + hread[0] + kk * 8 + 1], __ATOMIC_RELAXED, __HIP_MEMORY_SCOPE_AGENT);
        ub.q[0] = __hip_atomic_load(&hx64[pb + hread[1] + kk * 8],     __ATOMIC_RELAXED, __HIP_MEMORY_SCOPE_AGENT);
        ub.q[1] = __hip_atomic_load(&hx64[pb + hread[1] + kk * 8 + 1], __ATOMIC_RELAXED, __HIP_MEMORY_SCOPE_AGENT);
        const int ws0 = ((kk * 4 + quad) * 16 + m16) * 8;
        const bf16x8 bw0 = *(const bf16x8*)&wlds[ws0];
        const bf16x8 bw1 = *(const bf16x8*)&wlds[ws0 + 4096];
        const bf16x8 bw2 = *(const bf16x8*)&wlds[ws0 + 8192];
        acc[0][0] = __builtin_amdgcn_mfma_f32_16x16x32_bf16(ua.v, bw0, acc[0][0], 0, 0, 0);
        acc[0][1] = __builtin_amdgcn_mfma_f32_16x16x32_bf16(ua.v, bw1, acc[0][1], 0, 0, 0);
        acc[0][2] = __builtin_amdgcn_mfma_f32_16x16x32_bf16(ua.v, bw2, acc[0][2], 0, 0, 0);
        acc[1][0] = __builtin_amdgcn_mfma_f32_16x16x32_bf16(ub.v, bw0, acc[1][0], 0, 0, 0);
        acc[1][1] = __builtin_amdgcn_mfma_f32_16x16x32_bf16(ub.v, bw1, acc[1][1], 0, 0, 0);
        acc[1][2] = __builtin_amdgcn_mfma_f32_16x16x32_bf16(ub.v, bw2, acc[1][2], 0, 0, 0);
      }
    }

    const int pw = ((t + 1) & 1) << 16;      // ushort offset of write buffer (65536)
#pragma unroll
    for (int mt = 0; mt < 2; ++mt)
#pragma unroll
      for (int rg = 0; rg < 4; ++rg) {
        const float r = sigm(gv[mt][0][rg] + acc[mt][0][rg] + bb[0]);
        const float z = sigm(gv[mt][1][rg] + acc[mt][1][rg] + bb[1]);
        const float n = tanh_f(gv[mt][2][rg] + r * (acc[mt][2][rg] + bb[2]));
        float h = hreg[mt][rg];
        h = n + z * (h - n);                 // (1-z)*n + z*h
        hreg[mt][rg] = h;
        const unsigned short hb = f2bf(h);
        const int row = w * 32 + mt * 16 + quad * 4 + rg;
        __hip_atomic_store(&Hx[pw + row * 256 + col], hb, __ATOMIC_RELAXED, __HIP_MEMORY_SCOPE_AGENT);
        Hbf[(size_t)(row * 128 + t) * 256 + col] = hb;
      }
    __syncthreads();                          // all waves drain vmcnt(0) before barrier
    if (tid == 0)
      __hip_atomic_fetch_add(&flag[t + 1], 1u, __ATOMIC_RELAXED, __HIP_MEMORY_SCOPE_AGENT);
  }
}

// ---------------- contrastive loss + alpha (bf16 WC & P) ----------------
__global__ __launch_bounds__(256) void loss_k(
    const unsigned short* __restrict__ WC, const unsigned short* __restrict__ P,
    const int* __restrict__ neg, float* __restrict__ alpha, float* __restrict__ loss)
{
  const int t = blockIdx.x;                       // 0..126
  const int w = threadIdx.x >> 6, lane = threadIdx.x & 63;
  __shared__ float wls[4];
  float lsum = 0.f;
#pragma unroll 1
  for (int bi = 0; bi < 8; ++bi) {
    const int b = blockIdx.y * 32 + w * 8 + bi;
    const ushort4 wcu = *(const ushort4*)&WC[(size_t)(b * TDIM + t) * DDIM + lane * 4];
    float wc0 = bf2f_s(wcu.x), wc1 = bf2f_s(wcu.y), wc2 = bf2f_s(wcu.z), wc3 = bf2f_s(wcu.w);
    float s[16];
    {
      const ushort4 p4 = *(const ushort4*)&P[(size_t)(b * TDIM + t + 1) * DDIM + lane * 4];
      s[0] = wc0 * bf2f_s(p4.x) + wc1 * bf2f_s(p4.y) + wc2 * bf2f_s(p4.z) + wc3 * bf2f_s(p4.w);
    }
#pragma unroll
    for (int n = 0; n < 15; ++n) {
      const int rb = neg[(t * 15 + n) * 256 + b];
      const ushort4 p4 = *(const ushort4*)&P[(size_t)(rb * TDIM + t + 1) * DDIM + lane * 4];
      s[n + 1] = wc0 * bf2f_s(p4.x) + wc1 * bf2f_s(p4.y) + wc2 * bf2f_s(p4.z) + wc3 * bf2f_s(p4.w);
    }
#pragma unroll
    for (int n = 0; n < 16; ++n) {
      float v = s[n];
#pragma unroll
      for (int off = 32; off > 0; off >>= 1) v += __shfl_xor(v, off);
      s[n] = v * (1.f / 256.f);                   // mean over D
    }
    float mx = s[0];
#pragma unroll
    for (int n = 1; n < 16; ++n) mx = fmaxf(mx, s[n]);
    float se = 0.f;
#pragma unroll
    for (int n = 0; n < 16; ++n) se += __expf(s[n] - mx);
    lsum -= (s[0] - mx - __logf(se));             // -pos_ce
    if (t == TDIM - 2 && lane == 0) alpha[b] = s[0];   // alpha == sp[:,126]
  }
  if (lane == 0) wls[w] = lsum;
  __syncthreads();
  if (threadIdx.x == 0)
    atomicAdd(loss, (wls[0] + wls[1] + wls[2] + wls[3]) * (1.f / 256.f));
}

// ---------------- y = gelu(H[:,-1]@Wp1^T) @ Wp2^T (second half) ----------------
__global__ __launch_bounds__(256) void y_k(const float* __restrict__ Yh,
                                           const float* __restrict__ Wp2,
                                           float* __restrict__ y) {
  const int w = threadIdx.x >> 6, lane = threadIdx.x & 63;
  const int b = blockIdx.x * 4 + w;
  const float4 a = *(const float4*)&Yh[(size_t)b * 256 + lane * 4];
  const float4 q = *(const float4*)&Wp2[lane * 4];
  float s = a.x * q.x + a.y * q.y + a.z * q.z + a.w * q.w;
#pragma unroll
  for (int off = 32; off > 0; off >>= 1) s += __shfl_xor(s, off);
  if (lane == 0) y[b] = s;
}

// ---------------- launch ----------------
extern "C" void kernel_launch(void* const* d_in, const int* in_sizes, int n_in,
                              void* d_out, int out_size, void* d_ws, size_t ws_size,
                              hipStream_t stream) {
  (void)in_sizes; (void)n_in; (void)out_size; (void)ws_size;
  const float* P    = (const float*)d_in[0];
  const float* bih0 = (const float*)d_in[3];
  const float* bhh0 = (const float*)d_in[4];
  const float* bih1 = (const float*)d_in[7];
  const float* bhh1 = (const float*)d_in[8];

  char* ws = (char*)d_ws;
  float*          gi   = (float*)(ws + 0);                       // 100663296 B (later: G1bf)
  unsigned short* Xbf  = (unsigned short*)(ws + 100663296);      // 16777216 B (H1bf then Hbf)
  unsigned short* Pbf  = (unsigned short*)(ws + 117440512);      // 16777216 B
  unsigned short* WCb  = (unsigned short*)(ws + 134217728);      // 16777216 B (bf16 WC)
  unsigned short* wb   = (unsigned short*)(ws + 167772160);      // bf16 weights
  unsigned short* wih0b = wb;
  unsigned short* whh0b = wb + 196608;
  unsigned short* wih1b = wb + 393216;
  unsigned short* whh1b = wb + 589824;
  unsigned short* wbW   = wb + 786432;
  unsigned short* wp1b  = wb + 851968;
  unsigned short* wr1b  = wb + 917504;
  unsigned short* wr2b  = wb + 983040;
  float*          Yh   = (float*)(ws + 169869312);               // 262144 B
  unsigned short* Hx   = (unsigned short*)(ws + 170131456);      // 262144 B exchange
  unsigned int*   fl0  = (unsigned int*)(ws + 170393600);        // 129 u32
  unsigned int*   fl1  = (unsigned int*)(ws + 170394624);        // 129 u32
  unsigned short* G1bf = (unsigned short*)gi;                    // reuse gi region after L1

  float* out  = (float*)d_out;
  float* Hout = out;                  // 8388608
  float* Yout = out + 8388608;        // 256
  float* Rout = out + 8388864;        // 8388608
  float* Aout = out + 16777472;       // 256
  float* Lout = out + 16777728;       // 1

  hipMemsetAsync(ws + 170393600, 0, 2048, stream);   // both flag arrays
  hipMemsetAsync(Lout, 0, 4, stream);

  cvt_all<<<9216, 256, 0, stream>>>(
      P, Pbf,
      (const float*)d_in[1], wih0b, (const float*)d_in[2], whh0b,
      (const float*)d_in[5], wih1b, (const float*)d_in[6], whh1b,
      (const float*)d_in[9], wbW,   (const float*)d_in[10], wp1b,
      (const float*)d_in[12], wr1b, (const float*)d_in[13], wr2b);

  dim3 thr(256);
  // gi0 = Pbf @ Wih0^T + bih0   (natural layout)
  gemm_bf16<<<dim3(6, 256), thr, 0, stream>>>(Pbf, 256, wih0b, 256, bih0, gi, nullptr, 256, 768, 0);
  // layer 0 recurrence -> H1bf
  gru_rec<<<16, 512, 0, stream>>>(gi, whh0b, bhh0, Xbf, Hx, fl0);
  // gi1 = H1bf @ Wih1^T + bih1
  gemm_bf16<<<dim3(6, 256), thr, 0, stream>>>(Xbf, 256, wih1b, 256, bih1, gi, nullptr, 256, 768, 0);
  // layer 1 recurrence -> Hbf
  gru_rec<<<16, 512, 0, stream>>>(gi, whh1b, bhh1, Xbf, Hx, fl1);
  // Hout fp32 = expand(Hbf)  (8388608 floats -> n8 = 1048576)
  bf2f<<<4096, 256, 0, stream>>>(Xbf, Hout, 1048576);
  // WCbf = bf16(H @ W^T)
  gemm_bf16<<<dim3(2, 256), thr, 0, stream>>>(Xbf, 256, wbW, 256, nullptr, nullptr, WCb, 256, 256, 0);
  // G1 = gelu(H @ Wr1^T) bf16 (into old gi region; Pbf still needed by loss)
  gemm_bf16<<<dim3(2, 256), thr, 0, stream>>>(Xbf, 256, wr1b, 256, nullptr, nullptr, G1bf, 256, 256, 1);
  // R = G1 @ Wr2^T
  gemm_bf16<<<dim3(2, 256), thr, 0, stream>>>(G1bf, 256, wr2b, 256, nullptr, Rout, nullptr, 256, 256, 0);
  // Yh = gelu(H[:,127,:] @ Wp1^T)  (A rows strided by T*HID)
  gemm_bf16<<<dim3(2, 2), thr, 0, stream>>>(Xbf + 127 * 256, 32768, wp1b, 256, nullptr, Yh, nullptr, 256, 256, 1);
  y_k<<<64, 256, 0, stream>>>(Yh, (const float*)d_in[11], Yout);

  loss_k<<<dim3(127, 8), thr, 0, stream>>>(WCb, Pbf, (const int*)d_in[14], Aout, Lout);
}